// Round 1
// 258.192 us; speedup vs baseline: 1.0665x; 1.0665x over previous
//
#include <hip/hip_runtime.h>
#include <stdint.h>

#define EPSV 1e-7f
#define FDIM 512
#define ROWS 128      // rows of x per block, tile resident in LDS
#define BK 64         // k-chunk of W per stage
#define NROWS 65536   // 16*4096

typedef __bf16 bf16_t;
typedef bf16_t bf16x8 __attribute__((ext_vector_type(8)));
typedef unsigned short ushort8 __attribute__((ext_vector_type(8)));
typedef float f32x4 __attribute__((ext_vector_type(4)));

#define AS1 __attribute__((address_space(1)))
#define AS3 __attribute__((address_space(3)))

// RNE float -> bf16
__device__ __forceinline__ unsigned short f2bf(float f) {
  union { float f; unsigned int u; } c; c.f = f;
  unsigned int u = c.u;
  unsigned int r = u + 0x7fffu + ((u >> 16) & 1u);
  return (unsigned short)(r >> 16);
}
__device__ __forceinline__ float bf2f(unsigned short s) {
  union { unsigned int u; float f; } c; c.u = ((unsigned int)s) << 16;
  return c.f;
}

// tanh via hardware exp + rcp; clamped so e^{2x} can't overflow.
__device__ __forceinline__ float fast_tanh(float x) {
  x = fminf(15.0f, fmaxf(-15.0f, x));
  float t = __expf(2.0f * x);
  return 1.0f - 2.0f * __builtin_amdgcn_rcpf(t + 1.0f);
}

// Wt[n][k] = bf16(W[k][n]) via LDS tile transpose, both sides coalesced.
__global__ void convert_W(const float* __restrict__ W, unsigned short* __restrict__ Wt) {
  __shared__ unsigned short tile[32][34];
  const int t = threadIdx.x;
  const int tx = t & 31, ty = t >> 5;
  const int bn = blockIdx.x & 15, bk = blockIdx.x >> 4;
  const int k0 = bk * 32, n0 = bn * 32;
#pragma unroll
  for (int i = 0; i < 4; ++i) {
    int r = ty + i * 8;
    tile[r][tx] = f2bf(W[(size_t)(k0 + r) * FDIM + n0 + tx]);
  }
  __syncthreads();
#pragma unroll
  for (int i = 0; i < 4; ++i) {
    int r = ty + i * 8;
    Wt[(size_t)(n0 + r) * FDIM + k0 + tx] = tile[tx][r];
  }
}

// Issue async global->LDS stage of a 128xBK chunk of Wt into sB.
// Per wave: 2 iters x (8 rows x 8 blocks of 16B), wave-uniform LDS base,
// per-lane swizzled global source (phys block p holds logical p^(row&7)).
#define ISSUE_B(col0_, kb_)                                                    \
  do {                                                                         \
    _Pragma("unroll") for (int i_ = 0; i_ < 2; ++i_) {                         \
      const int rb_ = w * 16 + i_ * 8;                                         \
      const int rl_ = rb_ + (lane >> 3);                                       \
      const int j_ = (lane & 7) ^ (rl_ & 7);                                   \
      const unsigned short* g_ =                                               \
          Wt + (size_t)((col0_) + rl_) * FDIM + (kb_) + j_ * 8;                \
      unsigned short* l_ = (unsigned short*)(sB + rb_ * BK);                   \
      __builtin_amdgcn_global_load_lds((AS1 void*)(g_), (AS3 void*)(l_), 16,   \
                                       0, 0);                                  \
    }                                                                          \
  } while (0)

// One block = 128 rows, FULL N=512 (4 chunks of 128 sequentially).
// x tile resident in LDS as bf16 (staged once from fp32, swizzled).
// Produces: ppool[blk][512] = sum_row e[row]*x[row][f], and atomic sumE.
__global__ __launch_bounds__(512, 2) void fused_score_pool(
    const float* __restrict__ x, const unsigned short* __restrict__ Wt,
    const float* __restrict__ bvec, const float* __restrict__ uvec,
    float* __restrict__ ppool, float* __restrict__ sumE) {
  __shared__ alignas(16) unsigned short sA[ROWS * FDIM];  // 128 KB, swizzled
  __shared__ alignas(16) unsigned short sB[128 * BK];     // 16 KB, swizzled
  __shared__ float score_s[ROWS];
  __shared__ float e_s[ROWS];

  const int t = threadIdx.x;     // 0..511
  const int lane = t & 63;
  const int w = t >> 6;          // 0..7
  const int wm = w & 1;          // row half (64 rows)
  const int wn = w >> 1;         // col quarter (32 cols of the 128-chunk)
  const int quad = lane >> 4;
  const int l15 = lane & 15;
  const int m0 = blockIdx.x * ROWS;

  if (t < ROWS) score_s[t] = 0.0f;

  // ---- prologue: issue first B chunk so it flies under the A-stage ----
  ISSUE_B(0, 0);

  // ---- stage A resident: fp32 x -> bf16 LDS, 16B-block XOR swizzle ----
  // per wave per p: one full row (64 blocks x 16B), coalesced 2KB reads
#pragma unroll
  for (int p = 0; p < 16; ++p) {
    const int row = p * 8 + w;
    const float* g = x + (size_t)(m0 + row) * FDIM + lane * 8;
    float4 lo = *(const float4*)g;
    float4 hi = *(const float4*)(g + 4);
    ushort8 v;
    v[0] = f2bf(lo.x); v[1] = f2bf(lo.y); v[2] = f2bf(lo.z); v[3] = f2bf(lo.w);
    v[4] = f2bf(hi.x); v[5] = f2bf(hi.y); v[6] = f2bf(hi.z); v[7] = f2bf(hi.w);
    const int jp = lane ^ (row & 7);
    *(ushort8*)(void*)(sA + row * FDIM + jp * 8) = v;
  }
  __syncthreads();   // A tile + B chunk 0 ready

  float sc[4][4];
#pragma unroll
  for (int mi = 0; mi < 4; ++mi)
#pragma unroll
    for (int r = 0; r < 4; ++r) sc[mi][r] = 0.0f;

  for (int nc = 0; nc < 4; ++nc) {
    const int col0 = nc * 128;
    f32x4 acc[4][2];
#pragma unroll
    for (int mi = 0; mi < 4; ++mi)
#pragma unroll
      for (int ni = 0; ni < 2; ++ni) acc[mi][ni] = (f32x4){0.f, 0.f, 0.f, 0.f};

    for (int kc = 0; kc < 8; ++kc) {
      // ---- preload this chunk's B fragments to registers ----
      bf16x8 bfr[2][2];
#pragma unroll
      for (int ni = 0; ni < 2; ++ni)
#pragma unroll
        for (int ks = 0; ks < 2; ++ks) {
          const int nrow = wn * 32 + ni * 16 + l15;
          const int phys = (ks * 4 + quad) ^ (nrow & 7);
          bfr[ni][ks] = *(const bf16x8*)(const void*)(sB + nrow * BK + phys * 8);
        }
      __syncthreads();  // all waves done reading sB -> safe to overwrite

      // ---- issue next B chunk; its latency hides under the MFMAs ----
      const int s = nc * 8 + kc + 1;
      if (s < 32) ISSUE_B((s >> 3) * 128, (s & 7) * BK);

      // ---- MFMA: A from resident LDS, B from registers ----
#pragma unroll
      for (int ks = 0; ks < 2; ++ks) {
        bf16x8 af[4];
#pragma unroll
        for (int mi = 0; mi < 4; ++mi) {
          const int row = wm * 64 + mi * 16 + l15;
          const int phys = kc * 8 + ((ks * 4 + quad) ^ (row & 7));
          af[mi] = *(const bf16x8*)(const void*)(sA + row * FDIM + phys * 8);
        }
#pragma unroll
        for (int mi = 0; mi < 4; ++mi)
#pragma unroll
          for (int ni = 0; ni < 2; ++ni)
            acc[mi][ni] = __builtin_amdgcn_mfma_f32_16x16x32_bf16(
                af[mi], bfr[ni][ks], acc[mi][ni], 0, 0, 0);
      }
      __syncthreads();  // compiler drains vmcnt here -> next chunk ready
    }

    // ---- epilogue for this n-chunk: sc += u[n]*tanh(C + b[n]) ----
#pragma unroll
    for (int ni = 0; ni < 2; ++ni) {
      const int cl = col0 + wn * 32 + ni * 16 + l15;
      const float uu = uvec[cl], bb = bvec[cl];
#pragma unroll
      for (int mi = 0; mi < 4; ++mi)
#pragma unroll
        for (int r = 0; r < 4; ++r)
          sc[mi][r] += uu * fast_tanh(acc[mi][ni][r] + bb);
    }
  }

  // ---- reduce scores across the 16 column-lanes, land in score_s ----
#pragma unroll
  for (int mi = 0; mi < 4; ++mi)
#pragma unroll
    for (int r = 0; r < 4; ++r) {
      float v = sc[mi][r];
      v += __shfl_xor(v, 1); v += __shfl_xor(v, 2);
      v += __shfl_xor(v, 4); v += __shfl_xor(v, 8);
      if (l15 == 0)
        atomicAdd(&score_s[wm * 64 + mi * 16 + quad * 4 + r], v);
    }
  __syncthreads();

  // ---- e = exp(score); block partial of sumE ----
  if (t < ROWS) {
    const float e = __expf(score_s[t]);
    e_s[t] = e;
    float v = e;
    v += __shfl_xor(v, 1);  v += __shfl_xor(v, 2);  v += __shfl_xor(v, 4);
    v += __shfl_xor(v, 8);  v += __shfl_xor(v, 16); v += __shfl_xor(v, 32);
    if (lane == 0) atomicAdd(sumE, v);
  }
  __syncthreads();

  // ---- pooling from the resident tile: pp[f] = sum_row e[row]*x[row][f] ----
  float a[8];
#pragma unroll
  for (int jj = 0; jj < 8; ++jj) a[jj] = 0.0f;
#pragma unroll
  for (int rr = 0; rr < 16; ++rr) {
    const int row = w * 16 + rr;
    const int jp = lane ^ (row & 7);
    const ushort8 v = *(const ushort8*)(const void*)(sA + row * FDIM + jp * 8);
    const float wg = e_s[row];
#pragma unroll
    for (int jj = 0; jj < 8; ++jj) a[jj] += bf2f(v[jj]) * wg;
  }
  // cross-wave reduce via red[8][512] overlaid on sB (both 16 KB)
  float* red = (float*)sB;
  *(float4*)&red[w * FDIM + lane * 8]     = (float4){a[0], a[1], a[2], a[3]};
  *(float4*)&red[w * FDIM + lane * 8 + 4] = (float4){a[4], a[5], a[6], a[7]};
  __syncthreads();
  {
    float sv = 0.0f;
#pragma unroll
    for (int g = 0; g < 8; ++g) sv += red[g * FDIM + t];
    ppool[(size_t)blockIdx.x * FDIM + t] = sv;
  }
}

// out[b,f] = (sum over the 32 row-blocks of batch b) / (sumE + eps)
__global__ __launch_bounds__(256) void finalize(
    const float* __restrict__ ppool, const float* __restrict__ sumE,
    float* __restrict__ out) {
  const int i = blockIdx.x * 256 + threadIdx.x;   // 0..8191
  const int b = i >> 9, f = i & 511;
  const float* p = ppool + (size_t)b * 32 * FDIM + f;
  float s = 0.0f;
#pragma unroll
  for (int c = 0; c < 32; ++c) s += p[(size_t)c * FDIM];
  out[i] = s / (*sumE + EPSV);
}

extern "C" void kernel_launch(void* const* d_in, const int* in_sizes, int n_in,
                              void* d_out, int out_size, void* d_ws, size_t ws_size,
                              hipStream_t stream) {
  (void)in_sizes; (void)n_in; (void)out_size; (void)ws_size;
  const float* x = (const float*)d_in[0];
  const float* W = (const float*)d_in[1];
  const float* b = (const float*)d_in[2];
  const float* u = (const float*)d_in[3];
  float* out = (float*)d_out;

  // ws layout: Wt 512K | sumE (pad 256) | ppool 1M   (total ~1.55 MB)
  char* p = (char*)d_ws;
  unsigned short* Wt = (unsigned short*)p;  p += (size_t)FDIM * FDIM * 2;
  float* sumE = (float*)p;                  p += 256;
  float* ppool = (float*)p;                 p += (size_t)(NROWS / ROWS) * FDIM * 4;

  hipMemsetAsync(sumE, 0, sizeof(float), stream);
  convert_W<<<dim3(256), dim3(256), 0, stream>>>(W, Wt);
  fused_score_pool<<<dim3(NROWS / ROWS), dim3(512), 0, stream>>>(
      x, Wt, b, u, ppool, sumE);
  finalize<<<dim3(32), dim3(256), 0, stream>>>(ppool, sumE, out);
}

// Round 2
// 248.846 us; speedup vs baseline: 1.1065x; 1.0376x over previous
//
#include <hip/hip_runtime.h>
#include <stdint.h>

#define EPSV 1e-7f
#define FDIM 512
#define ROWS 128      // rows of x per block, tile resident in LDS
#define BK 32         // k-chunk of W per sB stage
#define PCOLS 256     // columns per N-pass (2 passes cover 512)
#define NROWS 65536   // 16*4096

typedef __bf16 bf16_t;
typedef bf16_t bf16x8 __attribute__((ext_vector_type(8)));
typedef unsigned short ushort8 __attribute__((ext_vector_type(8)));
typedef float f32x4 __attribute__((ext_vector_type(4)));

#define AS1 __attribute__((address_space(1)))
#define AS3 __attribute__((address_space(3)))

// RNE float -> bf16
__device__ __forceinline__ unsigned short f2bf(float f) {
  union { float f; unsigned int u; } c; c.f = f;
  unsigned int u = c.u;
  unsigned int r = u + 0x7fffu + ((u >> 16) & 1u);
  return (unsigned short)(r >> 16);
}
__device__ __forceinline__ float bf2f(unsigned short s) {
  union { unsigned int u; float f; } c; c.u = ((unsigned int)s) << 16;
  return c.f;
}

// tanh via hardware exp + rcp; clamped so e^{2x} can't overflow.
__device__ __forceinline__ float fast_tanh(float x) {
  x = fminf(15.0f, fmaxf(-15.0f, x));
  float t = __expf(2.0f * x);
  return 1.0f - 2.0f * __builtin_amdgcn_rcpf(t + 1.0f);
}

// Wt[n][k] = bf16(W[k][n]) via LDS tile transpose, both sides coalesced.
// Also zeroes sumE (runs before fused kernel in stream order).
__global__ void convert_W(const float* __restrict__ W, unsigned short* __restrict__ Wt,
                          float* __restrict__ sumE) {
  if (blockIdx.x == 0 && threadIdx.x == 0) *sumE = 0.0f;
  __shared__ unsigned short tile[32][34];
  const int t = threadIdx.x;
  const int tx = t & 31, ty = t >> 5;
  const int bn = blockIdx.x & 15, bk = blockIdx.x >> 4;
  const int k0 = bk * 32, n0 = bn * 32;
#pragma unroll
  for (int i = 0; i < 4; ++i) {
    int r = ty + i * 8;
    tile[r][tx] = f2bf(W[(size_t)(k0 + r) * FDIM + n0 + tx]);
  }
  __syncthreads();
#pragma unroll
  for (int i = 0; i < 4; ++i) {
    int r = ty + i * 8;
    Wt[(size_t)(n0 + r) * FDIM + k0 + tx] = tile[tx][r];
  }
}

// Async global->LDS stage of a PCOLSxBK chunk of Wt into sB[buf_].
// sB row = 64B (4 x 16B blocks); physical block p at row r holds logical
// block p ^ ((r>>2)&3)  (same involution the frag reads apply).
// Per wave: 2 instrs x (16 rows x 4 blocks), wave-uniform LDS base.
#define ISSUE_B(buf_, pass_, kc_)                                              \
  do {                                                                         \
    _Pragma("unroll") for (int i_ = 0; i_ < 2; ++i_) {                         \
      const int rb_ = (w * 2 + i_) * 16;                                       \
      const int rl_ = rb_ + (lane >> 2);                                       \
      const int j_ = (lane & 3) ^ ((rl_ >> 2) & 3);                            \
      const unsigned short* g_ =                                               \
          Wt + (size_t)((pass_) * PCOLS + rl_) * FDIM + (kc_) * BK + j_ * 8;   \
      unsigned short* l_ = (unsigned short*)(&sB[buf_][0] + rb_ * BK);         \
      __builtin_amdgcn_global_load_lds((AS1 void*)(g_), (AS3 void*)(l_), 16,   \
                                       0, 0);                                  \
    }                                                                          \
  } while (0)

// One block = 128 rows, full N=512 as 2 passes of 256 cols.
// x tile resident in LDS as bf16 (staged once). Double-buffered sB,
// ONE barrier per k-chunk, next chunk prefetched at top of iteration.
// 8 waves as 2(M)x4(N), wave tile 64x64 -> 8 ds_read_b128 per 16 MFMA.
__global__ __launch_bounds__(512, 2) void fused_score_pool(
    const float* __restrict__ x, const unsigned short* __restrict__ Wt,
    const float* __restrict__ bvec, const float* __restrict__ uvec,
    float* __restrict__ ppool, float* __restrict__ sumE) {
  __shared__ alignas(16) unsigned short sA[ROWS * FDIM];    // 128 KB resident
  __shared__ alignas(16) unsigned short sB[2][PCOLS * BK];  // 2 x 16 KB

  const int t = threadIdx.x;     // 0..511
  const int lane = t & 63;
  const int w = t >> 6;          // 0..7
  const int wm = w & 1;          // row half (64 rows)
  const int wn = w >> 1;         // 0..3: col quarter of the 256-col pass
  const int quad = lane >> 4;
  const int l15 = lane & 15;
  const int m0 = blockIdx.x * ROWS;

  // ---- prologue: first B chunk flies under the A-stage ----
  ISSUE_B(0, 0, 0);

  // ---- stage A resident: fp32 x -> bf16 LDS, 16B-block XOR swizzle ----
#pragma unroll
  for (int p = 0; p < 16; ++p) {
    const int row = p * 8 + w;
    const float* g = x + (size_t)(m0 + row) * FDIM + lane * 8;
    float4 lo = *(const float4*)g;
    float4 hi = *(const float4*)(g + 4);
    ushort8 v;
    v[0] = f2bf(lo.x); v[1] = f2bf(lo.y); v[2] = f2bf(lo.z); v[3] = f2bf(lo.w);
    v[4] = f2bf(hi.x); v[5] = f2bf(hi.y); v[6] = f2bf(hi.z); v[7] = f2bf(hi.w);
    const int jp = lane ^ (row & 7);
    *(ushort8*)(void*)(sA + row * FDIM + jp * 8) = v;
  }
  __syncthreads();   // A tile + B chunk 0 ready

  float sc[4][4];
#pragma unroll
  for (int mi = 0; mi < 4; ++mi)
#pragma unroll
    for (int r = 0; r < 4; ++r) sc[mi][r] = 0.0f;

  int cur = 0;
  for (int pass = 0; pass < 2; ++pass) {
    f32x4 acc[4][4];
#pragma unroll
    for (int mi = 0; mi < 4; ++mi)
#pragma unroll
      for (int ni = 0; ni < 4; ++ni) acc[mi][ni] = (f32x4){0.f, 0.f, 0.f, 0.f};

#pragma unroll 2
    for (int kc = 0; kc < 16; ++kc) {
      // ---- prefetch next chunk into the other buffer (overwrite is safe:
      //      previous iteration's barrier closed all reads of it) ----
      const int s = pass * 16 + kc + 1;
      if (s < 32) ISSUE_B(cur ^ 1, (s >> 4), (s & 15));

      // ---- frag reads from current buffers ----
      bf16x8 bfr[4], af[4];
#pragma unroll
      for (int ni = 0; ni < 4; ++ni) {
        const int r = wn * 64 + ni * 16 + l15;
        const int phys = quad ^ ((r >> 2) & 3);
        bfr[ni] = *(const bf16x8*)(const void*)(&sB[cur][0] + r * BK + phys * 8);
      }
#pragma unroll
      for (int mi = 0; mi < 4; ++mi) {
        const int row = wm * 64 + mi * 16 + l15;
        const int g = kc * 4 + quad;
        const int phys = g ^ (row & 7);
        af[mi] = *(const bf16x8*)(const void*)(sA + row * FDIM + phys * 8);
      }

      // ---- 16 MFMA; their issue time covers the prefetch L2 latency ----
#pragma unroll
      for (int mi = 0; mi < 4; ++mi)
#pragma unroll
        for (int ni = 0; ni < 4; ++ni)
          acc[mi][ni] = __builtin_amdgcn_mfma_f32_16x16x32_bf16(
              af[mi], bfr[ni], acc[mi][ni], 0, 0, 0);

      __syncthreads();   // drains vmcnt (prefetch landed) + closes reads
      cur ^= 1;
    }

    // ---- epilogue for this pass: sc += u[n]*tanh(C + b[n]) ----
#pragma unroll
    for (int ni = 0; ni < 4; ++ni) {
      const int cl = pass * PCOLS + wn * 64 + ni * 16 + l15;
      const float uu = uvec[cl], bb = bvec[cl];
#pragma unroll
      for (int mi = 0; mi < 4; ++mi)
#pragma unroll
        for (int r = 0; r < 4; ++r)
          sc[mi][r] += uu * fast_tanh(acc[mi][ni][r] + bb);
    }
  }

  // ---- post-GEMM overlays on sB (safe after last barrier) ----
  float* sBf = (float*)&sB[0][0];
  float* red = sBf;                  // [8][512] f32 = 16 KB (all of sB[0])
  float* score_s = sBf + 4096;       // 128 f32 (start of sB[1])
  float* e_s = sBf + 4096 + 128;     // 128 f32

  if (t < ROWS) score_s[t] = 0.0f;
  __syncthreads();

  // ---- reduce scores: sum over 16 col-lanes, then across col-waves ----
#pragma unroll
  for (int mi = 0; mi < 4; ++mi)
#pragma unroll
    for (int r = 0; r < 4; ++r) {
      float v = sc[mi][r];
      v += __shfl_xor(v, 1); v += __shfl_xor(v, 2);
      v += __shfl_xor(v, 4); v += __shfl_xor(v, 8);
      if (l15 == 0)
        atomicAdd(&score_s[wm * 64 + mi * 16 + quad * 4 + r], v);
    }
  __syncthreads();

  // ---- e = exp(score); block partial of sumE ----
  if (t < ROWS) {
    const float e = __expf(score_s[t]);
    e_s[t] = e;
    float v = e;
    v += __shfl_xor(v, 1);  v += __shfl_xor(v, 2);  v += __shfl_xor(v, 4);
    v += __shfl_xor(v, 8);  v += __shfl_xor(v, 16); v += __shfl_xor(v, 32);
    if (lane == 0) atomicAdd(sumE, v);
  }
  __syncthreads();

  // ---- pooling from the resident tile ----
  float a[8];
#pragma unroll
  for (int jj = 0; jj < 8; ++jj) a[jj] = 0.0f;
#pragma unroll
  for (int rr = 0; rr < 16; ++rr) {
    const int row = w * 16 + rr;
    const int jp = lane ^ (row & 7);
    const ushort8 v = *(const ushort8*)(const void*)(sA + row * FDIM + jp * 8);
    const float wg = e_s[row];
#pragma unroll
    for (int jj = 0; jj < 8; ++jj) a[jj] += bf2f(v[jj]) * wg;
  }
  *(float4*)&red[w * FDIM + lane * 8]     = (float4){a[0], a[1], a[2], a[3]};
  *(float4*)&red[w * FDIM + lane * 8 + 4] = (float4){a[4], a[5], a[6], a[7]};
  __syncthreads();
  {
    float sv = 0.0f;
#pragma unroll
    for (int g = 0; g < 8; ++g) sv += red[g * FDIM + t];
    ppool[(size_t)blockIdx.x * FDIM + t] = sv;
  }
}

// out[b,f] = (sum over the 32 row-blocks of batch b) / (sumE + eps)
__global__ __launch_bounds__(256) void finalize(
    const float* __restrict__ ppool, const float* __restrict__ sumE,
    float* __restrict__ out) {
  const int i = blockIdx.x * 256 + threadIdx.x;   // 0..8191
  const int b = i >> 9, f = i & 511;
  const float* p = ppool + (size_t)b * 32 * FDIM + f;
  float s = 0.0f;
#pragma unroll
  for (int c = 0; c < 32; ++c) s += p[(size_t)c * FDIM];
  out[i] = s / (*sumE + EPSV);
}

extern "C" void kernel_launch(void* const* d_in, const int* in_sizes, int n_in,
                              void* d_out, int out_size, void* d_ws, size_t ws_size,
                              hipStream_t stream) {
  (void)in_sizes; (void)n_in; (void)out_size; (void)ws_size;
  const float* x = (const float*)d_in[0];
  const float* W = (const float*)d_in[1];
  const float* b = (const float*)d_in[2];
  const float* u = (const float*)d_in[3];
  float* out = (float*)d_out;

  // ws layout: Wt 512K | sumE (pad 256) | ppool 1M   (total ~1.55 MB)
  char* p = (char*)d_ws;
  unsigned short* Wt = (unsigned short*)p;  p += (size_t)FDIM * FDIM * 2;
  float* sumE = (float*)p;                  p += 256;
  float* ppool = (float*)p;                 p += (size_t)(NROWS / ROWS) * FDIM * 4;

  convert_W<<<dim3(256), dim3(256), 0, stream>>>(W, Wt, sumE);
  fused_score_pool<<<dim3(NROWS / ROWS), dim3(512), 0, stream>>>(
      x, Wt, b, u, ppool, sumE);
  finalize<<<dim3(32), dim3(256), 0, stream>>>(ppool, sumE, out);
}

// Round 3
// 236.491 us; speedup vs baseline: 1.1643x; 1.0522x over previous
//
#include <hip/hip_runtime.h>
#include <stdint.h>

#define EPSV 1e-7f
#define FDIM 512
#define ROWS 64       // rows of x per block, tile resident in LDS (64 KB)
#define NROWS 65536   // 16*4096
#define NBLK (NROWS / ROWS)   // 1024

typedef __bf16 bf16_t;
typedef bf16_t bf16x8 __attribute__((ext_vector_type(8)));
typedef unsigned short ushort8 __attribute__((ext_vector_type(8)));
typedef float f32x4 __attribute__((ext_vector_type(4)));

// RNE float -> bf16
__device__ __forceinline__ unsigned short f2bf(float f) {
  union { float f; unsigned int u; } c; c.f = f;
  unsigned int u = c.u;
  unsigned int r = u + 0x7fffu + ((u >> 16) & 1u);
  return (unsigned short)(r >> 16);
}
__device__ __forceinline__ float bf2f(unsigned short s) {
  union { unsigned int u; float f; } c; c.u = ((unsigned int)s) << 16;
  return c.f;
}

// tanh via hardware exp + rcp; clamped so e^{2x} can't overflow.
__device__ __forceinline__ float fast_tanh(float x) {
  x = fminf(15.0f, fmaxf(-15.0f, x));
  float t = __expf(2.0f * x);
  return 1.0f - 2.0f * __builtin_amdgcn_rcpf(t + 1.0f);
}

// Wt2[k>>5][n][k&31] = bf16(W[k][n])  (k-chunked so a wave's B-fragment
// load = 16 rows x 64B contiguous = fully coalesced from L2).
// Also zeroes sumE.
__global__ void convert_W(const float* __restrict__ W, unsigned short* __restrict__ Wt2,
                          float* __restrict__ sumE) {
  if (blockIdx.x == 0 && threadIdx.x == 0) *sumE = 0.0f;
  __shared__ unsigned short tile[32][34];
  const int t = threadIdx.x;
  const int tx = t & 31, ty = t >> 5;
  const int bn = blockIdx.x & 15, bk = blockIdx.x >> 4;
  const int k0 = bk * 32, n0 = bn * 32;
#pragma unroll
  for (int i = 0; i < 4; ++i) {
    int r = ty + i * 8;
    tile[r][tx] = f2bf(W[(size_t)(k0 + r) * FDIM + n0 + tx]);
  }
  __syncthreads();
#pragma unroll
  for (int i = 0; i < 4; ++i) {
    int r = ty + i * 8;
    // n = n0 + r, k = k0 + tx  ->  Wt2[(k0>>5)*16384 + n*32 + tx]
    Wt2[(size_t)(k0 >> 5) * (FDIM * 32) + (size_t)(n0 + r) * 32 + tx] = tile[tx][r];
  }
}

// One block = 64 rows x full N=512. 8 waves as 1(M) x 8(N): wave tile 64x64.
// A resident in LDS bf16 (swizzled); B fragments loaded straight from L2 to
// registers (no sB, NO barriers in the K loop). 2 blocks/CU, 4 waves/SIMD.
__global__ __launch_bounds__(512, 4) void fused_score_pool(
    const float* __restrict__ x, const unsigned short* __restrict__ Wt2,
    const float* __restrict__ bvec, const float* __restrict__ uvec,
    float* __restrict__ ppool, float* __restrict__ sumE) {
  __shared__ alignas(16) unsigned short sA[ROWS * FDIM];  // 64 KB
  __shared__ float score_s[ROWS];
  __shared__ float e_s[ROWS];

  const int t = threadIdx.x;     // 0..511
  const int lane = t & 63;
  const int w = t >> 6;          // 0..7 : owns cols w*64 .. w*64+63
  const int quad = lane >> 4;
  const int l15 = lane & 15;
  const int m0 = blockIdx.x * ROWS;

  if (t < ROWS) score_s[t] = 0.0f;

  // ---- stage A: fp32 x -> bf16 LDS, 16B-block XOR swizzle (proven) ----
#pragma unroll
  for (int p = 0; p < 8; ++p) {
    const int row = p * 8 + w;
    const float* g = x + (size_t)(m0 + row) * FDIM + lane * 8;
    float4 lo = *(const float4*)g;
    float4 hi = *(const float4*)(g + 4);
    ushort8 v;
    v[0] = f2bf(lo.x); v[1] = f2bf(lo.y); v[2] = f2bf(lo.z); v[3] = f2bf(lo.w);
    v[4] = f2bf(hi.x); v[5] = f2bf(hi.y); v[6] = f2bf(hi.z); v[7] = f2bf(hi.w);
    const int jp = lane ^ (row & 7);
    *(ushort8*)(void*)(sA + row * FDIM + jp * 8) = v;
  }
  __syncthreads();   // the ONLY barrier before the epilogue

  // ---- K loop: barrier-free. B from global (L2-resident Wt2), A from LDS.
  f32x4 acc[4][4];
#pragma unroll
  for (int mi = 0; mi < 4; ++mi)
#pragma unroll
    for (int ni = 0; ni < 4; ++ni) acc[mi][ni] = (f32x4){0.f, 0.f, 0.f, 0.f};

  // lane's B base: col = w*64 + ni*16 + l15, k-slot = quad*8 within chunk
  const unsigned short* bp = Wt2 + (size_t)(w * 64 + l15) * 32 + quad * 8;

#pragma unroll 2
  for (int kc = 0; kc < 16; ++kc) {
    bf16x8 bfr[4], af[4];
#pragma unroll
    for (int ni = 0; ni < 4; ++ni)
      bfr[ni] = *(const bf16x8*)(const void*)(bp + (size_t)kc * (FDIM * 32) + ni * 512);
#pragma unroll
    for (int mi = 0; mi < 4; ++mi) {
      const int row = mi * 16 + l15;
      const int phys = (kc * 4 + quad) ^ (row & 7);
      af[mi] = *(const bf16x8*)(const void*)(sA + row * FDIM + phys * 8);
    }
    __builtin_amdgcn_s_setprio(1);
#pragma unroll
    for (int mi = 0; mi < 4; ++mi)
#pragma unroll
      for (int ni = 0; ni < 4; ++ni)
        acc[mi][ni] = __builtin_amdgcn_mfma_f32_16x16x32_bf16(
            af[mi], bfr[ni], acc[mi][ni], 0, 0, 0);
    __builtin_amdgcn_s_setprio(0);
  }

  // ---- epilogue: sc = sum_n u[n]*tanh(C + b[n]); reduce over 16 col-lanes
  float uu[4], bb[4];
#pragma unroll
  for (int ni = 0; ni < 4; ++ni) {
    const int cl = w * 64 + ni * 16 + l15;
    uu[ni] = uvec[cl];
    bb[ni] = bvec[cl];
  }
#pragma unroll
  for (int mi = 0; mi < 4; ++mi)
#pragma unroll
    for (int r = 0; r < 4; ++r) {
      float v = 0.0f;
#pragma unroll
      for (int ni = 0; ni < 4; ++ni)
        v += uu[ni] * fast_tanh(acc[mi][ni][r] + bb[ni]);
      v += __shfl_xor(v, 1); v += __shfl_xor(v, 2);
      v += __shfl_xor(v, 4); v += __shfl_xor(v, 8);
      if (l15 == 0)
        atomicAdd(&score_s[mi * 16 + quad * 4 + r], v);
    }
  __syncthreads();

  // ---- e = exp(score); block partial of sumE (wave 0 only) ----
  if (t < ROWS) {
    const float e = __expf(score_s[t]);
    e_s[t] = e;
    float v = e;
    v += __shfl_xor(v, 1);  v += __shfl_xor(v, 2);  v += __shfl_xor(v, 4);
    v += __shfl_xor(v, 8);  v += __shfl_xor(v, 16); v += __shfl_xor(v, 32);
    if (lane == 0) atomicAdd(sumE, v);
  }
  __syncthreads();

  // ---- pooling: one thread per column, sum over the 64 resident rows ----
  {
    const int col = t;                 // 0..511
    const int jblk = col >> 3, jj = col & 7;
    float s = 0.0f;
#pragma unroll 8
    for (int row = 0; row < ROWS; ++row) {
      const int phys = ((jblk ^ (row & 7)) << 3) + jj;
      s += bf2f(sA[row * FDIM + phys]) * e_s[row];
    }
    ppool[(size_t)blockIdx.x * FDIM + col] = s;
  }
}

// out[b,f] = (sum over the 64 row-blocks of batch b) / (sumE + eps)
__global__ __launch_bounds__(256) void finalize(
    const float* __restrict__ ppool, const float* __restrict__ sumE,
    float* __restrict__ out) {
  const int i = blockIdx.x * 256 + threadIdx.x;   // 0..8191
  const int b = i >> 9, f = i & 511;
  const float* p = ppool + (size_t)b * 64 * FDIM + f;
  float s = 0.0f;
#pragma unroll
  for (int c = 0; c < 64; ++c) s += p[(size_t)c * FDIM];
  out[i] = s / (*sumE + EPSV);
}

extern "C" void kernel_launch(void* const* d_in, const int* in_sizes, int n_in,
                              void* d_out, int out_size, void* d_ws, size_t ws_size,
                              hipStream_t stream) {
  (void)in_sizes; (void)n_in; (void)out_size; (void)ws_size;
  const float* x = (const float*)d_in[0];
  const float* W = (const float*)d_in[1];
  const float* b = (const float*)d_in[2];
  const float* u = (const float*)d_in[3];
  float* out = (float*)d_out;

  // ws layout: Wt2 512K | sumE (pad 256) | ppool 2M   (~2.6 MB)
  char* p = (char*)d_ws;
  unsigned short* Wt2 = (unsigned short*)p;  p += (size_t)FDIM * FDIM * 2;
  float* sumE = (float*)p;                   p += 256;
  float* ppool = (float*)p;                  p += (size_t)NBLK * FDIM * 4;

  convert_W<<<dim3(256), dim3(256), 0, stream>>>(W, Wt2, sumE);
  fused_score_pool<<<dim3(NBLK), dim3(512), 0, stream>>>(
      x, Wt2, b, u, ppool, sumE);
  finalize<<<dim3(32), dim3(256), 0, stream>>>(ppool, sumE, out);
}